// Round 13
// baseline (310.434 us; speedup 1.0000x reference)
//
#include <hip/hip_runtime.h>

#define NN 100000
#define EE 1000000
#define FF 128
#define HH 64
#define GG 128
#define NB 391   // scan blocks: 391*256 = 100096 >= NN
#define MMB 1563 // matmul blocks: ceil(NN/64)
#define GCB 2048 // persistent gconv blocks (8/CU)

__device__ inline unsigned short f2bf(float f) {
    unsigned u = __float_as_uint(f);
    u += 0x7fffu + ((u >> 16) & 1u);
    return (unsigned short)(u >> 16);
}
__device__ inline float bf2f(unsigned short h) {
    return __uint_as_float((unsigned)h << 16);
}

// ---------- CSR build ----------
__global__ void k_hist(const int* __restrict__ ei, int* __restrict__ cnt) {
    int e = blockIdx.x * 256 + threadIdx.x;
    if (e < EE) atomicAdd(&cnt[ei[EE + e]], 1);
}

__global__ void k_scan1(const int* __restrict__ cnt, int* __restrict__ part,
                        float* __restrict__ dis) {
    int i = blockIdx.x * 256 + threadIdx.x;
    int c = (i < NN) ? cnt[i] : 0;
    if (i < NN) dis[i] = rsqrtf((float)(c + 1));
    int v = (i < NN) ? c : 0;
    for (int o = 1; o < 64; o <<= 1) v += __shfl_xor(v, o);
    __shared__ int ws[4];
    if ((threadIdx.x & 63) == 0) ws[threadIdx.x >> 6] = v;
    __syncthreads();
    if (threadIdx.x == 0) part[blockIdx.x] = ws[0] + ws[1] + ws[2] + ws[3];
}

__global__ void k_scan2(int* __restrict__ part) {   // exclusive scan, 1 block
    __shared__ int buf[512];
    int t = threadIdx.x;
    int v = (t < NB) ? part[t] : 0;
    buf[t] = v; __syncthreads();
    for (int o = 1; o < 512; o <<= 1) {
        int u = (t >= o) ? buf[t - o] : 0;
        __syncthreads();
        buf[t] += u;
        __syncthreads();
    }
    if (t < NB) part[t] = buf[t] - v;
}

__global__ void k_scan3(const int* __restrict__ cnt, const int* __restrict__ part,
                        int* __restrict__ row_ptr, int* __restrict__ cursor) {
    int i = blockIdx.x * 256 + threadIdx.x;
    int v = (i < NN) ? cnt[i] : 0;
    int lane = threadIdx.x & 63, w = threadIdx.x >> 6;
    int incl = v;
    for (int o = 1; o < 64; o <<= 1) { int u = __shfl_up(incl, o); if (lane >= o) incl += u; }
    __shared__ int ws[4];
    if (lane == 63) ws[w] = incl;
    __syncthreads();
    int woff = 0;
    for (int k = 0; k < w; ++k) woff += ws[k];
    int excl = incl - v + woff + part[blockIdx.x];
    if (i < NN) {
        row_ptr[i] = excl;
        cursor[i]  = excl;
    }
    if (i == 0) row_ptr[NN] = EE;
}

__global__ void k_place(const int* __restrict__ ei, int* __restrict__ cursor,
                        int* __restrict__ srcs) {
    int e = blockIdx.x * 256 + threadIdx.x;
    if (e < EE) {
        int d = ei[EE + e];
        int p = atomicAdd(&cursor[d], 1);
        srcs[p] = ei[e];
    }
}

// ---------- matmul: int8 row-quantized output; W staged in 64-row halves ----------
// 16KB LDS -> 8 blocks/CU -> full 32-wave occupancy (was 32KB/5 blocks/37%).
template<int K, int XBF>
__global__ __launch_bounds__(256) void
k_matmul_b(const void* __restrict__ Xv, const float* __restrict__ W,
           const float* __restrict__ dis, unsigned* __restrict__ Y8,
           float* __restrict__ S) {
    __shared__ float Wl[64 * HH];          // 16 KB
    const int lane = threadIdx.x & 63;
    const int wv   = threadIdx.x >> 6;
    const int c4   = (lane & 15) * 4;
    const int rsg  = lane >> 4;
    const int r0   = blockIdx.x * 64 + wv * 16 + rsg * 4;

    const char* Xb = (const char*)Xv;
    const size_t rb = (size_t)K * (XBF ? 2 : 4);
    const char* xr0; const char* xr1; const char* xr2; const char* xr3;
    {
        int a = r0, b_ = r0 + 1, c = r0 + 2, d = r0 + 3;
        if (a > NN - 1) a = NN - 1;
        if (b_ > NN - 1) b_ = NN - 1;
        if (c > NN - 1) c = NN - 1;
        if (d > NN - 1) d = NN - 1;
        xr0 = Xb + (size_t)a * rb; xr1 = Xb + (size_t)b_ * rb;
        xr2 = Xb + (size_t)c * rb; xr3 = Xb + (size_t)d * rb;
    }
    float4 acc0 = {0,0,0,0}, acc1 = {0,0,0,0}, acc2 = {0,0,0,0}, acc3 = {0,0,0,0};

    for (int ks = 0; ks < K; ks += 64) {
        __syncthreads();                   // protect Wl before overwrite
        for (int i = threadIdx.x; i < 64 * HH; i += 256) Wl[i] = W[ks * HH + i];
        __syncthreads();
#pragma unroll 8
        for (int k4 = 0; k4 < 16; ++k4) {
            const int kk = ks + k4 * 4;    // global k
            float4 x0, x1, x2, x3;
            if (XBF) {
                ushort4 u0 = *(const ushort4*)(xr0 + kk * 2);
                ushort4 u1 = *(const ushort4*)(xr1 + kk * 2);
                ushort4 u2 = *(const ushort4*)(xr2 + kk * 2);
                ushort4 u3 = *(const ushort4*)(xr3 + kk * 2);
                x0 = {bf2f(u0.x), bf2f(u0.y), bf2f(u0.z), bf2f(u0.w)};
                x1 = {bf2f(u1.x), bf2f(u1.y), bf2f(u1.z), bf2f(u1.w)};
                x2 = {bf2f(u2.x), bf2f(u2.y), bf2f(u2.z), bf2f(u2.w)};
                x3 = {bf2f(u3.x), bf2f(u3.y), bf2f(u3.z), bf2f(u3.w)};
            } else {
                x0 = *(const float4*)(xr0 + kk * 4);
                x1 = *(const float4*)(xr1 + kk * 4);
                x2 = *(const float4*)(xr2 + kk * 4);
                x3 = *(const float4*)(xr3 + kk * 4);
            }
            const float4 w0 = *(const float4*)&Wl[(k4 * 4 + 0) * HH + c4];
            const float4 w1 = *(const float4*)&Wl[(k4 * 4 + 1) * HH + c4];
            const float4 w2 = *(const float4*)&Wl[(k4 * 4 + 2) * HH + c4];
            const float4 w3 = *(const float4*)&Wl[(k4 * 4 + 3) * HH + c4];
#define FMA4(A, XS) \
            A.x = fmaf(XS.x, w0.x, A.x); A.y = fmaf(XS.x, w0.y, A.y); \
            A.z = fmaf(XS.x, w0.z, A.z); A.w = fmaf(XS.x, w0.w, A.w); \
            A.x = fmaf(XS.y, w1.x, A.x); A.y = fmaf(XS.y, w1.y, A.y); \
            A.z = fmaf(XS.y, w1.z, A.z); A.w = fmaf(XS.y, w1.w, A.w); \
            A.x = fmaf(XS.z, w2.x, A.x); A.y = fmaf(XS.z, w2.y, A.y); \
            A.z = fmaf(XS.z, w2.z, A.z); A.w = fmaf(XS.z, w2.w, A.w); \
            A.x = fmaf(XS.w, w3.x, A.x); A.y = fmaf(XS.w, w3.y, A.y); \
            A.z = fmaf(XS.w, w3.z, A.z); A.w = fmaf(XS.w, w3.w, A.w);
            FMA4(acc0, x0) FMA4(acc1, x1) FMA4(acc2, x2) FMA4(acc3, x3)
#undef FMA4
        }
    }
#define STORE(I, A) { \
        const int r = r0 + I; \
        if (r < NN) { \
            const float d = dis[r]; \
            const float ax = A.x * d, ay = A.y * d, az = A.z * d, aw = A.w * d; \
            float m = fmaxf(fmaxf(fabsf(ax), fabsf(ay)), fmaxf(fabsf(az), fabsf(aw))); \
            m = fmaxf(m, __shfl_xor(m, 1)); m = fmaxf(m, __shfl_xor(m, 2)); \
            m = fmaxf(m, __shfl_xor(m, 4)); m = fmaxf(m, __shfl_xor(m, 8)); \
            const float inv = 127.0f / m; \
            int q0 = __float2int_rn(ax * inv), q1 = __float2int_rn(ay * inv); \
            int q2 = __float2int_rn(az * inv), q3 = __float2int_rn(aw * inv); \
            if (m == 0.0f) { q0 = q1 = q2 = q3 = 0; } \
            const unsigned pk = (q0 & 0xff) | ((q1 & 0xff) << 8) | \
                                ((q2 & 0xff) << 16) | ((q3 & 0xff) << 24); \
            Y8[(size_t)r * 16 + (c4 >> 2)] = pk; \
            if (c4 == 0) S[r] = m * (1.0f / 127.0f); \
        } }
    STORE(0, acc0) STORE(1, acc1) STORE(2, acc2) STORE(3, acc3)
#undef STORE
}

// ---------- gather conv: persistent waves, grid-stride over nodes ----------
template<bool POOL>
__global__ __launch_bounds__(256) void
k_gconv(const int* __restrict__ row_ptr, const int* __restrict__ srcs,
        const float* __restrict__ dis, const unsigned* __restrict__ H8,
        const float* __restrict__ S, const float* __restrict__ b,
        unsigned short* __restrict__ Out, const int* __restrict__ batch,
        float* __restrict__ g) {
    const int lane = threadIdx.x & 63;
    const int li   = lane & 15;       // word index within row
    const int qr   = lane >> 4;       // row slot 0..3 per load
    const float bl = b[lane];         // hoisted: constant across nodes

    for (int node = blockIdx.x * 4 + (threadIdx.x >> 6); node < NN; node += GCB * 4) {
        const int p0   = row_ptr[node];
        const int deg  = row_ptr[node + 1] - p0;
        const int nbatch = (deg + 8) >> 3;     // items = deg+1 (self)

        float ac0 = 0.f, ac1 = 0.f, ac2 = 0.f, ac3 = 0.f;

#define IDX(bi, dA, dB) { \
        const int iA = 8 * (bi) + qr, iB = iA + 4; \
        dA = srcs[p0 + (iA < deg ? iA : 0)]; \
        dB = srcs[p0 + (iB < deg ? iB : 0)]; }
#define VAL(bi, sA, sB, vA, vB, gA, gB) { \
        const int iA = 8 * (bi) + qr, iB = iA + 4; \
        const int rA = (iA < deg) ? sA : node; \
        const int rB = (iB < deg) ? sB : node; \
        vA = H8[(size_t)rA * 16 + li];  gA = S[rA]; \
        vB = H8[(size_t)rB * 16 + li];  gB = S[rB]; }
#define CONSUME(bi, vA, vB, gA, gB) { \
        const int iA = 8 * (bi) + qr, iB = iA + 4; \
        const float s0 = (iA <= deg) ? gA : 0.f; \
        const float s1 = (iB <= deg) ? gB : 0.f; \
        ac0 = fmaf(s0, (float)(signed char)(vA      ), ac0); \
        ac1 = fmaf(s0, (float)(signed char)(vA >> 8 ), ac1); \
        ac2 = fmaf(s0, (float)(signed char)(vA >> 16), ac2); \
        ac3 = fmaf(s0, (float)(signed char)(vA >> 24), ac3); \
        ac0 = fmaf(s1, (float)(signed char)(vB      ), ac0); \
        ac1 = fmaf(s1, (float)(signed char)(vB >> 8 ), ac1); \
        ac2 = fmaf(s1, (float)(signed char)(vB >> 16), ac2); \
        ac3 = fmaf(s1, (float)(signed char)(vB >> 24), ac3); }

        int sA0, sA1, sB0, sB1;
        unsigned vA0, vA1;
        float gA0, gA1;
        IDX(0, sA0, sA1);
        VAL(0, sA0, sA1, vA0, vA1, gA0, gA1);
        IDX(1, sB0, sB1);
        for (int bi = 1; bi < nbatch; ++bi) {
            unsigned vB0, vB1;
            float gB0, gB1;
            VAL(bi, sB0, sB1, vB0, vB1, gB0, gB1);
            IDX(bi + 1, sB0, sB1);               // clamped beyond end
            CONSUME(bi - 1, vA0, vA1, gA0, gA1);
            vA0 = vB0; vA1 = vB1; gA0 = gB0; gA1 = gB1;
        }
        CONSUME(nbatch - 1, vA0, vA1, gA0, gA1);
#undef IDX
#undef VAL
#undef CONSUME

        // reduce across the 4 row slots
        ac0 += __shfl_xor(ac0, 16); ac0 += __shfl_xor(ac0, 32);
        ac1 += __shfl_xor(ac1, 16); ac1 += __shfl_xor(ac1, 32);
        ac2 += __shfl_xor(ac2, 16); ac2 += __shfl_xor(ac2, 32);
        ac3 += __shfl_xor(ac3, 16); ac3 += __shfl_xor(ac3, 32);
        // redistribute so lane holds col = lane
        const float c0 = __shfl(ac0, lane >> 2);
        const float c1 = __shfl(ac1, lane >> 2);
        const float c2 = __shfl(ac2, lane >> 2);
        const float c3 = __shfl(ac3, lane >> 2);
        const int m = lane & 3;
        const float acc = (m == 0) ? c0 : (m == 1) ? c1 : (m == 2) ? c2 : c3;

        float v = acc * dis[node] + bl;
        v = fmaxf(v, 0.0f);
        if (POOL) {
            unsafeAtomicAdd(&g[(size_t)batch[node] * HH + lane], v);
        } else {
            Out[(size_t)node * HH + lane] = f2bf(v);   // plain store: keep A in L2
        }
    }
}

// ---------- head ----------
__global__ void k_head1(const float* __restrict__ g, const float* __restrict__ W,
                        const float* __restrict__ b, float* __restrict__ g2) {
    const int idx = blockIdx.x * 256 + threadIdx.x;
    const int row = idx >> 6;
    const int col = idx & 63;
    const float* gr = g + (size_t)row * HH;
    float acc = b[col];
#pragma unroll
    for (int k = 0; k < HH; ++k) acc = fmaf(gr[k], W[k * HH + col], acc);
    g2[idx] = acc > 0.0f ? acc : 0.0f;
}

__global__ void k_head2(const float* __restrict__ g2, const float* __restrict__ W,
                        const float* __restrict__ b, float* __restrict__ out) {
    const int r = threadIdx.x;
    if (r >= GG) return;
    const float* gr = g2 + (size_t)r * HH;
    float acc = 0.0f;
#pragma unroll
    for (int k = 0; k < HH; ++k) acc = fmaf(gr[k], W[k], acc);
    out[r] = acc + b[0];
}

extern "C" void kernel_launch(void* const* d_in, const int* in_sizes, int n_in,
                              void* d_out, int out_size, void* d_ws, size_t ws_size,
                              hipStream_t stream) {
    const float* x   = (const float*)d_in[0];
    const int*   ei  = (const int*)d_in[1];
    const int*   bat = (const int*)d_in[2];
    const float* W1  = (const float*)d_in[3];
    const float* b1  = (const float*)d_in[4];
    const float* W2  = (const float*)d_in[5];
    const float* b2  = (const float*)d_in[6];
    const float* Wl1 = (const float*)d_in[7];
    const float* bl1 = (const float*)d_in[8];
    const float* Wl2 = (const float*)d_in[9];
    const float* bl2 = (const float*)d_in[10];
    float* out = (float*)d_out;

    char* w = (char*)d_ws;
    float*    dis     = (float*)(w);                  // 400,128 B
    int*      cnt     = (int*)  (w + 400128);         // 400,128 B
    int*      row_ptr = (int*)  (w + 800256);         // 400,384 B
    int*      cursor  = (int*)  (w + 1200640);        // 400,128 B
    int*      part    = (int*)  (w + 1600768);        // 2,048 B
    int*      srcs    = (int*)  (w + 1602816);        // 4,000,000 B
    float*    S       = (float*)(w + 5602816);        // 400,128 B
    unsigned* H8      = (unsigned*)(w + 6002944);     // 6,400,000 B
    unsigned short* A = (unsigned short*)(w + 12402944); // bf16, 12,800,000 B
    float*    g       = (float*)(w + 25202944);       // pool + head scratch
    float*    g2      = g + GG * HH;

    // ---- CSR build ----
    hipMemsetAsync(cnt, 0, (size_t)NN * sizeof(int), stream);
    k_hist <<<(EE + 255) / 256, 256, 0, stream>>>(ei, cnt);
    k_scan1<<<NB, 256, 0, stream>>>(cnt, part, dis);
    k_scan2<<<1, 512, 0, stream>>>(part);
    k_scan3<<<NB, 256, 0, stream>>>(cnt, part, row_ptr, cursor);
    k_place<<<(EE + 255) / 256, 256, 0, stream>>>(ei, cursor, srcs);

    // ---- conv1 ----
    k_matmul_b<FF, 0><<<MMB, 256, 0, stream>>>(x, W1, dis, H8, S);
    k_gconv<false><<<GCB, 256, 0, stream>>>(row_ptr, srcs, dis, H8, S, b1, A, nullptr, nullptr);

    // ---- conv2 (pool fused) ----
    k_matmul_b<HH, 1><<<MMB, 256, 0, stream>>>(A, W2, dis, H8, S);
    hipMemsetAsync(g, 0, (size_t)GG * HH * sizeof(float), stream);
    k_gconv<true><<<GCB, 256, 0, stream>>>(row_ptr, srcs, dis, H8, S, b2, nullptr, bat, g);

    // ---- head ----
    k_head1<<<(GG * HH) / 256, 256, 0, stream>>>(g, Wl1, bl1, g2);
    k_head2<<<1, 128, 0, stream>>>(g2, Wl2, bl2, out);
}

// Round 14
// 297.013 us; speedup vs baseline: 1.0452x; 1.0452x over previous
//
#include <hip/hip_runtime.h>

#define NN 100000
#define EE 1000000
#define FF 128
#define HH 64
#define GG 128
#define NB 391   // scan blocks: 391*256 = 100096 >= NN
#define MMB 1563 // matmul blocks: ceil(NN/64)
#define GCB 2048 // persistent gconv blocks (8/CU)

__device__ inline unsigned short f2bf(float f) {
    unsigned u = __float_as_uint(f);
    u += 0x7fffu + ((u >> 16) & 1u);
    return (unsigned short)(u >> 16);
}
__device__ inline float bf2f(unsigned short h) {
    return __uint_as_float((unsigned)h << 16);
}

// ---------- CSR build ----------
__global__ void k_hist(const int* __restrict__ ei, int* __restrict__ cnt) {
    int e = blockIdx.x * 256 + threadIdx.x;
    if (e < EE) atomicAdd(&cnt[ei[EE + e]], 1);
}

__global__ void k_scan1(const int* __restrict__ cnt, int* __restrict__ part,
                        float* __restrict__ dis) {
    int i = blockIdx.x * 256 + threadIdx.x;
    int c = (i < NN) ? cnt[i] : 0;
    if (i < NN) dis[i] = rsqrtf((float)(c + 1));
    int v = (i < NN) ? c : 0;
    for (int o = 1; o < 64; o <<= 1) v += __shfl_xor(v, o);
    __shared__ int ws[4];
    if ((threadIdx.x & 63) == 0) ws[threadIdx.x >> 6] = v;
    __syncthreads();
    if (threadIdx.x == 0) part[blockIdx.x] = ws[0] + ws[1] + ws[2] + ws[3];
}

__global__ void k_scan2(int* __restrict__ part) {   // exclusive scan, 1 block
    __shared__ int buf[512];
    int t = threadIdx.x;
    int v = (t < NB) ? part[t] : 0;
    buf[t] = v; __syncthreads();
    for (int o = 1; o < 512; o <<= 1) {
        int u = (t >= o) ? buf[t - o] : 0;
        __syncthreads();
        buf[t] += u;
        __syncthreads();
    }
    if (t < NB) part[t] = buf[t] - v;
}

__global__ void k_scan3(const int* __restrict__ cnt, const int* __restrict__ part,
                        int* __restrict__ row_ptr, int* __restrict__ cursor) {
    int i = blockIdx.x * 256 + threadIdx.x;
    int v = (i < NN) ? cnt[i] : 0;
    int lane = threadIdx.x & 63, w = threadIdx.x >> 6;
    int incl = v;
    for (int o = 1; o < 64; o <<= 1) { int u = __shfl_up(incl, o); if (lane >= o) incl += u; }
    __shared__ int ws[4];
    if (lane == 63) ws[w] = incl;
    __syncthreads();
    int woff = 0;
    for (int k = 0; k < w; ++k) woff += ws[k];
    int excl = incl - v + woff + part[blockIdx.x];
    if (i < NN) {
        row_ptr[i] = excl;
        cursor[i]  = excl;
    }
    if (i == 0) row_ptr[NN] = EE;
}

// ---------- matmul body: int8 row-quantized out; W staged in 64-row halves (16KB) ----------
template<int K, int XBF>
__device__ __forceinline__ void
mm_body(const void* __restrict__ Xv, const float* __restrict__ W,
        const float* __restrict__ dis, unsigned* __restrict__ Y8,
        float* __restrict__ S, float* __restrict__ Wl, int bid) {
    const int lane = threadIdx.x & 63;
    const int wv   = threadIdx.x >> 6;
    const int c4   = (lane & 15) * 4;
    const int rsg  = lane >> 4;
    const int r0   = bid * 64 + wv * 16 + rsg * 4;

    const char* Xb = (const char*)Xv;
    const size_t rb = (size_t)K * (XBF ? 2 : 4);
    const char* xr0; const char* xr1; const char* xr2; const char* xr3;
    {
        int a = r0, b_ = r0 + 1, c = r0 + 2, d = r0 + 3;
        if (a > NN - 1) a = NN - 1;
        if (b_ > NN - 1) b_ = NN - 1;
        if (c > NN - 1) c = NN - 1;
        if (d > NN - 1) d = NN - 1;
        xr0 = Xb + (size_t)a * rb; xr1 = Xb + (size_t)b_ * rb;
        xr2 = Xb + (size_t)c * rb; xr3 = Xb + (size_t)d * rb;
    }
    float4 acc0 = {0,0,0,0}, acc1 = {0,0,0,0}, acc2 = {0,0,0,0}, acc3 = {0,0,0,0};

    for (int ks = 0; ks < K; ks += 64) {
        __syncthreads();
        for (int i = threadIdx.x; i < 64 * HH; i += 256) Wl[i] = W[ks * HH + i];
        __syncthreads();
#pragma unroll 8
        for (int k4 = 0; k4 < 16; ++k4) {
            const int kk = ks + k4 * 4;
            float4 x0, x1, x2, x3;
            if (XBF) {
                ushort4 u0 = *(const ushort4*)(xr0 + kk * 2);
                ushort4 u1 = *(const ushort4*)(xr1 + kk * 2);
                ushort4 u2 = *(const ushort4*)(xr2 + kk * 2);
                ushort4 u3 = *(const ushort4*)(xr3 + kk * 2);
                x0 = {bf2f(u0.x), bf2f(u0.y), bf2f(u0.z), bf2f(u0.w)};
                x1 = {bf2f(u1.x), bf2f(u1.y), bf2f(u1.z), bf2f(u1.w)};
                x2 = {bf2f(u2.x), bf2f(u2.y), bf2f(u2.z), bf2f(u2.w)};
                x3 = {bf2f(u3.x), bf2f(u3.y), bf2f(u3.z), bf2f(u3.w)};
            } else {
                x0 = *(const float4*)(xr0 + kk * 4);
                x1 = *(const float4*)(xr1 + kk * 4);
                x2 = *(const float4*)(xr2 + kk * 4);
                x3 = *(const float4*)(xr3 + kk * 4);
            }
            const float4 w0 = *(const float4*)&Wl[(k4 * 4 + 0) * HH + c4];
            const float4 w1 = *(const float4*)&Wl[(k4 * 4 + 1) * HH + c4];
            const float4 w2 = *(const float4*)&Wl[(k4 * 4 + 2) * HH + c4];
            const float4 w3 = *(const float4*)&Wl[(k4 * 4 + 3) * HH + c4];
#define FMA4(A, XS) \
            A.x = fmaf(XS.x, w0.x, A.x); A.y = fmaf(XS.x, w0.y, A.y); \
            A.z = fmaf(XS.x, w0.z, A.z); A.w = fmaf(XS.x, w0.w, A.w); \
            A.x = fmaf(XS.y, w1.x, A.x); A.y = fmaf(XS.y, w1.y, A.y); \
            A.z = fmaf(XS.y, w1.z, A.z); A.w = fmaf(XS.y, w1.w, A.w); \
            A.x = fmaf(XS.z, w2.x, A.x); A.y = fmaf(XS.z, w2.y, A.y); \
            A.z = fmaf(XS.z, w2.z, A.z); A.w = fmaf(XS.z, w2.w, A.w); \
            A.x = fmaf(XS.w, w3.x, A.x); A.y = fmaf(XS.w, w3.y, A.y); \
            A.z = fmaf(XS.w, w3.z, A.z); A.w = fmaf(XS.w, w3.w, A.w);
            FMA4(acc0, x0) FMA4(acc1, x1) FMA4(acc2, x2) FMA4(acc3, x3)
#undef FMA4
        }
    }
#define STORE(I, A) { \
        const int r = r0 + I; \
        if (r < NN) { \
            const float d = dis[r]; \
            const float ax = A.x * d, ay = A.y * d, az = A.z * d, aw = A.w * d; \
            float m = fmaxf(fmaxf(fabsf(ax), fabsf(ay)), fmaxf(fabsf(az), fabsf(aw))); \
            m = fmaxf(m, __shfl_xor(m, 1)); m = fmaxf(m, __shfl_xor(m, 2)); \
            m = fmaxf(m, __shfl_xor(m, 4)); m = fmaxf(m, __shfl_xor(m, 8)); \
            const float inv = 127.0f / m; \
            int q0 = __float2int_rn(ax * inv), q1 = __float2int_rn(ay * inv); \
            int q2 = __float2int_rn(az * inv), q3 = __float2int_rn(aw * inv); \
            if (m == 0.0f) { q0 = q1 = q2 = q3 = 0; } \
            const unsigned pk = (q0 & 0xff) | ((q1 & 0xff) << 8) | \
                                ((q2 & 0xff) << 16) | ((q3 & 0xff) << 24); \
            Y8[(size_t)r * 16 + (c4 >> 2)] = pk; \
            if (c4 == 0) S[r] = m * (1.0f / 127.0f); \
        } }
    STORE(0, acc0) STORE(1, acc1) STORE(2, acc2) STORE(3, acc3)
#undef STORE
}

template<int K, int XBF>
__global__ __launch_bounds__(256) void
k_matmul_b(const void* __restrict__ X, const float* __restrict__ W,
           const float* __restrict__ dis, unsigned* __restrict__ Y8,
           float* __restrict__ S) {
    __shared__ float Wl[64 * HH];
    mm_body<K, XBF>(X, W, dis, Y8, S, Wl, blockIdx.x);
}

// fused: blocks [0,MMB) run matmul-1 (K=128, 16KB LDS -> 8 blk/CU);
// blocks [MMB,..) place edges (store-queue-bound; co-schedules with matmul).
__global__ __launch_bounds__(256) void
k_mm1_place(const float* __restrict__ X, const float* __restrict__ W,
            const float* __restrict__ dis, unsigned* __restrict__ Y8,
            float* __restrict__ S, const int* __restrict__ ei,
            int* __restrict__ cursor, int* __restrict__ srcs) {
    __shared__ float Wl[64 * HH];
    if (blockIdx.x < MMB) {
        mm_body<FF, 0>(X, W, dis, Y8, S, Wl, blockIdx.x);
    } else {
        int e = (blockIdx.x - MMB) * 256 + threadIdx.x;
        if (e < EE) {
            int d = ei[EE + e];
            int p = atomicAdd(&cursor[d], 1);
            srcs[p] = ei[e];
        }
    }
}

// ---------- gather conv: persistent waves, grid-stride over nodes ----------
template<bool POOL>
__global__ __launch_bounds__(256) void
k_gconv(const int* __restrict__ row_ptr, const int* __restrict__ srcs,
        const float* __restrict__ dis, const unsigned* __restrict__ H8,
        const float* __restrict__ S, const float* __restrict__ b,
        unsigned short* __restrict__ Out, const int* __restrict__ batch,
        float* __restrict__ g) {
    const int lane = threadIdx.x & 63;
    const int li   = lane & 15;       // word index within row
    const int qr   = lane >> 4;       // row slot 0..3 per load
    const float bl = b[lane];         // hoisted: constant across nodes

    for (int node = blockIdx.x * 4 + (threadIdx.x >> 6); node < NN; node += GCB * 4) {
        const int p0   = row_ptr[node];
        const int deg  = row_ptr[node + 1] - p0;
        const int nbatch = (deg + 8) >> 3;     // items = deg+1 (self)

        float ac0 = 0.f, ac1 = 0.f, ac2 = 0.f, ac3 = 0.f;

#define IDX(bi, dA, dB) { \
        const int iA = 8 * (bi) + qr, iB = iA + 4; \
        dA = srcs[p0 + (iA < deg ? iA : 0)]; \
        dB = srcs[p0 + (iB < deg ? iB : 0)]; }
#define VAL(bi, sA, sB, vA, vB, gA, gB) { \
        const int iA = 8 * (bi) + qr, iB = iA + 4; \
        const int rA = (iA < deg) ? sA : node; \
        const int rB = (iB < deg) ? sB : node; \
        vA = H8[(size_t)rA * 16 + li];  gA = S[rA]; \
        vB = H8[(size_t)rB * 16 + li];  gB = S[rB]; }
#define CONSUME(bi, vA, vB, gA, gB) { \
        const int iA = 8 * (bi) + qr, iB = iA + 4; \
        const float s0 = (iA <= deg) ? gA : 0.f; \
        const float s1 = (iB <= deg) ? gB : 0.f; \
        ac0 = fmaf(s0, (float)(signed char)(vA      ), ac0); \
        ac1 = fmaf(s0, (float)(signed char)(vA >> 8 ), ac1); \
        ac2 = fmaf(s0, (float)(signed char)(vA >> 16), ac2); \
        ac3 = fmaf(s0, (float)(signed char)(vA >> 24), ac3); \
        ac0 = fmaf(s1, (float)(signed char)(vB      ), ac0); \
        ac1 = fmaf(s1, (float)(signed char)(vB >> 8 ), ac1); \
        ac2 = fmaf(s1, (float)(signed char)(vB >> 16), ac2); \
        ac3 = fmaf(s1, (float)(signed char)(vB >> 24), ac3); }

        int sA0, sA1, sB0, sB1;
        unsigned vA0, vA1;
        float gA0, gA1;
        IDX(0, sA0, sA1);
        VAL(0, sA0, sA1, vA0, vA1, gA0, gA1);
        IDX(1, sB0, sB1);
        for (int bi = 1; bi < nbatch; ++bi) {
            unsigned vB0, vB1;
            float gB0, gB1;
            VAL(bi, sB0, sB1, vB0, vB1, gB0, gB1);
            IDX(bi + 1, sB0, sB1);               // clamped beyond end
            CONSUME(bi - 1, vA0, vA1, gA0, gA1);
            vA0 = vB0; vA1 = vB1; gA0 = gB0; gA1 = gB1;
        }
        CONSUME(nbatch - 1, vA0, vA1, gA0, gA1);
#undef IDX
#undef VAL
#undef CONSUME

        // reduce across the 4 row slots
        ac0 += __shfl_xor(ac0, 16); ac0 += __shfl_xor(ac0, 32);
        ac1 += __shfl_xor(ac1, 16); ac1 += __shfl_xor(ac1, 32);
        ac2 += __shfl_xor(ac2, 16); ac2 += __shfl_xor(ac2, 32);
        ac3 += __shfl_xor(ac3, 16); ac3 += __shfl_xor(ac3, 32);
        // redistribute so lane holds col = lane
        const float c0 = __shfl(ac0, lane >> 2);
        const float c1 = __shfl(ac1, lane >> 2);
        const float c2 = __shfl(ac2, lane >> 2);
        const float c3 = __shfl(ac3, lane >> 2);
        const int m = lane & 3;
        const float acc = (m == 0) ? c0 : (m == 1) ? c1 : (m == 2) ? c2 : c3;

        float v = acc * dis[node] + bl;
        v = fmaxf(v, 0.0f);
        if (POOL) {
            unsafeAtomicAdd(&g[(size_t)batch[node] * HH + lane], v);
        } else {
            Out[(size_t)node * HH + lane] = f2bf(v);   // plain store: keep A in L2
        }
    }
}

// ---------- head ----------
__global__ void k_head1(const float* __restrict__ g, const float* __restrict__ W,
                        const float* __restrict__ b, float* __restrict__ g2) {
    const int idx = blockIdx.x * 256 + threadIdx.x;
    const int row = idx >> 6;
    const int col = idx & 63;
    const float* gr = g + (size_t)row * HH;
    float acc = b[col];
#pragma unroll
    for (int k = 0; k < HH; ++k) acc = fmaf(gr[k], W[k * HH + col], acc);
    g2[idx] = acc > 0.0f ? acc : 0.0f;
}

__global__ void k_head2(const float* __restrict__ g2, const float* __restrict__ W,
                        const float* __restrict__ b, float* __restrict__ out) {
    const int r = threadIdx.x;
    if (r >= GG) return;
    const float* gr = g2 + (size_t)r * HH;
    float acc = 0.0f;
#pragma unroll
    for (int k = 0; k < HH; ++k) acc = fmaf(gr[k], W[k], acc);
    out[r] = acc + b[0];
}

extern "C" void kernel_launch(void* const* d_in, const int* in_sizes, int n_in,
                              void* d_out, int out_size, void* d_ws, size_t ws_size,
                              hipStream_t stream) {
    const float* x   = (const float*)d_in[0];
    const int*   ei  = (const int*)d_in[1];
    const int*   bat = (const int*)d_in[2];
    const float* W1  = (const float*)d_in[3];
    const float* b1  = (const float*)d_in[4];
    const float* W2  = (const float*)d_in[5];
    const float* b2  = (const float*)d_in[6];
    const float* Wl1 = (const float*)d_in[7];
    const float* bl1 = (const float*)d_in[8];
    const float* Wl2 = (const float*)d_in[9];
    const float* bl2 = (const float*)d_in[10];
    float* out = (float*)d_out;

    char* w = (char*)d_ws;
    float*    dis     = (float*)(w);                  // 400,128 B
    int*      cnt     = (int*)  (w + 400128);         // 400,128 B
    int*      row_ptr = (int*)  (w + 800256);         // 400,384 B
    int*      cursor  = (int*)  (w + 1200640);        // 400,128 B
    int*      part    = (int*)  (w + 1600768);        // 2,048 B
    int*      srcs    = (int*)  (w + 1602816);        // 4,000,000 B
    float*    S       = (float*)(w + 5602816);        // 400,128 B
    unsigned* H8      = (unsigned*)(w + 6002944);     // 6,400,000 B
    unsigned short* A = (unsigned short*)(w + 12402944); // bf16, 12,800,000 B
    float*    g       = (float*)(w + 25202944);       // pool + head scratch
    float*    g2      = g + GG * HH;

    // ---- CSR build ----
    hipMemsetAsync(cnt, 0, (size_t)NN * sizeof(int), stream);
    k_hist <<<(EE + 255) / 256, 256, 0, stream>>>(ei, cnt);
    k_scan1<<<NB, 256, 0, stream>>>(cnt, part, dis);
    k_scan2<<<1, 512, 0, stream>>>(part);
    k_scan3<<<NB, 256, 0, stream>>>(cnt, part, row_ptr, cursor);

    // ---- conv1 matmul fused with CSR edge placement ----
    k_mm1_place<<<MMB + (EE + 255) / 256, 256, 0, stream>>>(x, W1, dis, H8, S, ei, cursor, srcs);
    k_gconv<false><<<GCB, 256, 0, stream>>>(row_ptr, srcs, dis, H8, S, b1, A, nullptr, nullptr);

    // ---- conv2 (pool fused) ----
    k_matmul_b<HH, 1><<<MMB, 256, 0, stream>>>(A, W2, dis, H8, S);
    hipMemsetAsync(g, 0, (size_t)GG * HH * sizeof(float), stream);
    k_gconv<true><<<GCB, 256, 0, stream>>>(row_ptr, srcs, dis, H8, S, b2, nullptr, bat, g);

    // ---- head ----
    k_head1<<<(GG * HH) / 256, 256, 0, stream>>>(g, Wl1, bl1, g2);
    k_head2<<<1, 128, 0, stream>>>(g2, Wl2, bl2, out);
}

// Round 15
// 271.307 us; speedup vs baseline: 1.1442x; 1.0947x over previous
//
#include <hip/hip_runtime.h>

#define NN 100000
#define EE 1000000
#define FF 128
#define HH 64
#define GG 128
#define NB 391   // scan blocks: 391*256 = 100096 >= NN
#define MMB 1563 // matmul blocks: ceil(NN/64)
#define GCB 2048 // persistent gconv blocks (8/CU)

__device__ inline unsigned short f2bf(float f) {
    unsigned u = __float_as_uint(f);
    u += 0x7fffu + ((u >> 16) & 1u);
    return (unsigned short)(u >> 16);
}
__device__ inline float bf2f(unsigned short h) {
    return __uint_as_float((unsigned)h << 16);
}

// ---------- CSR build ----------
__global__ void k_hist(const int* __restrict__ ei, int* __restrict__ cnt) {
    int e = blockIdx.x * 256 + threadIdx.x;
    if (e < EE) atomicAdd(&cnt[ei[EE + e]], 1);
}

__global__ void k_scan1(const int* __restrict__ cnt, int* __restrict__ part,
                        float* __restrict__ dis) {
    int i = blockIdx.x * 256 + threadIdx.x;
    int c = (i < NN) ? cnt[i] : 0;
    if (i < NN) dis[i] = rsqrtf((float)(c + 1));
    int v = (i < NN) ? c : 0;
    for (int o = 1; o < 64; o <<= 1) v += __shfl_xor(v, o);
    __shared__ int ws[4];
    if ((threadIdx.x & 63) == 0) ws[threadIdx.x >> 6] = v;
    __syncthreads();
    if (threadIdx.x == 0) part[blockIdx.x] = ws[0] + ws[1] + ws[2] + ws[3];
}

__global__ void k_scan2(int* __restrict__ part) {   // exclusive scan, 1 block
    __shared__ int buf[512];
    int t = threadIdx.x;
    int v = (t < NB) ? part[t] : 0;
    buf[t] = v; __syncthreads();
    for (int o = 1; o < 512; o <<= 1) {
        int u = (t >= o) ? buf[t - o] : 0;
        __syncthreads();
        buf[t] += u;
        __syncthreads();
    }
    if (t < NB) part[t] = buf[t] - v;
}

__global__ void k_scan3(const int* __restrict__ cnt, const int* __restrict__ part,
                        int* __restrict__ row_ptr, int* __restrict__ cursor) {
    int i = blockIdx.x * 256 + threadIdx.x;
    int v = (i < NN) ? cnt[i] : 0;
    int lane = threadIdx.x & 63, w = threadIdx.x >> 6;
    int incl = v;
    for (int o = 1; o < 64; o <<= 1) { int u = __shfl_up(incl, o); if (lane >= o) incl += u; }
    __shared__ int ws[4];
    if (lane == 63) ws[w] = incl;
    __syncthreads();
    int woff = 0;
    for (int k = 0; k < w; ++k) woff += ws[k];
    int excl = incl - v + woff + part[blockIdx.x];
    if (i < NN) {
        row_ptr[i] = excl;
        cursor[i]  = excl;
    }
    if (i == 0) row_ptr[NN] = EE;
}

// ---------- matmul body (R12 exact: single-stage W, K*HH LDS) ----------
template<int K, int XBF>
__device__ __forceinline__ void
mm_body(const void* __restrict__ Xv, const float* __restrict__ W,
        const float* __restrict__ dis, unsigned* __restrict__ Y8,
        float* __restrict__ S, float* __restrict__ Wl, int bid) {
    for (int i = threadIdx.x; i < K * HH; i += 256) Wl[i] = W[i];
    __syncthreads();
    const int lane = threadIdx.x & 63;
    const int wv   = threadIdx.x >> 6;
    const int c4   = (lane & 15) * 4;
    const int rsg  = lane >> 4;
    const int r0   = bid * 64 + wv * 16 + rsg * 4;

    const char* Xb = (const char*)Xv;
    const size_t rb = (size_t)K * (XBF ? 2 : 4);
    const char* xr0; const char* xr1; const char* xr2; const char* xr3;
    {
        int a = r0, b_ = r0 + 1, c = r0 + 2, d = r0 + 3;
        if (a > NN - 1) a = NN - 1;
        if (b_ > NN - 1) b_ = NN - 1;
        if (c > NN - 1) c = NN - 1;
        if (d > NN - 1) d = NN - 1;
        xr0 = Xb + (size_t)a * rb; xr1 = Xb + (size_t)b_ * rb;
        xr2 = Xb + (size_t)c * rb; xr3 = Xb + (size_t)d * rb;
    }
    float4 acc0 = {0,0,0,0}, acc1 = {0,0,0,0}, acc2 = {0,0,0,0}, acc3 = {0,0,0,0};

#pragma unroll 8
    for (int k4 = 0; k4 < K / 4; ++k4) {
        float4 x0, x1, x2, x3;
        if (XBF) {
            ushort4 u0 = *(const ushort4*)(xr0 + k4 * 8);
            ushort4 u1 = *(const ushort4*)(xr1 + k4 * 8);
            ushort4 u2 = *(const ushort4*)(xr2 + k4 * 8);
            ushort4 u3 = *(const ushort4*)(xr3 + k4 * 8);
            x0 = {bf2f(u0.x), bf2f(u0.y), bf2f(u0.z), bf2f(u0.w)};
            x1 = {bf2f(u1.x), bf2f(u1.y), bf2f(u1.z), bf2f(u1.w)};
            x2 = {bf2f(u2.x), bf2f(u2.y), bf2f(u2.z), bf2f(u2.w)};
            x3 = {bf2f(u3.x), bf2f(u3.y), bf2f(u3.z), bf2f(u3.w)};
        } else {
            x0 = *(const float4*)(xr0 + k4 * 16);
            x1 = *(const float4*)(xr1 + k4 * 16);
            x2 = *(const float4*)(xr2 + k4 * 16);
            x3 = *(const float4*)(xr3 + k4 * 16);
        }
        const float4 w0 = *(const float4*)&Wl[(k4 * 4 + 0) * HH + c4];
        const float4 w1 = *(const float4*)&Wl[(k4 * 4 + 1) * HH + c4];
        const float4 w2 = *(const float4*)&Wl[(k4 * 4 + 2) * HH + c4];
        const float4 w3 = *(const float4*)&Wl[(k4 * 4 + 3) * HH + c4];
#define FMA4(A, XS) \
        A.x = fmaf(XS.x, w0.x, A.x); A.y = fmaf(XS.x, w0.y, A.y); \
        A.z = fmaf(XS.x, w0.z, A.z); A.w = fmaf(XS.x, w0.w, A.w); \
        A.x = fmaf(XS.y, w1.x, A.x); A.y = fmaf(XS.y, w1.y, A.y); \
        A.z = fmaf(XS.y, w1.z, A.z); A.w = fmaf(XS.y, w1.w, A.w); \
        A.x = fmaf(XS.z, w2.x, A.x); A.y = fmaf(XS.z, w2.y, A.y); \
        A.z = fmaf(XS.z, w2.z, A.z); A.w = fmaf(XS.z, w2.w, A.w); \
        A.x = fmaf(XS.w, w3.x, A.x); A.y = fmaf(XS.w, w3.y, A.y); \
        A.z = fmaf(XS.w, w3.z, A.z); A.w = fmaf(XS.w, w3.w, A.w);
        FMA4(acc0, x0) FMA4(acc1, x1) FMA4(acc2, x2) FMA4(acc3, x3)
#undef FMA4
    }
#define STORE(I, A) { \
        const int r = r0 + I; \
        if (r < NN) { \
            const float d = dis[r]; \
            const float ax = A.x * d, ay = A.y * d, az = A.z * d, aw = A.w * d; \
            float m = fmaxf(fmaxf(fabsf(ax), fabsf(ay)), fmaxf(fabsf(az), fabsf(aw))); \
            m = fmaxf(m, __shfl_xor(m, 1)); m = fmaxf(m, __shfl_xor(m, 2)); \
            m = fmaxf(m, __shfl_xor(m, 4)); m = fmaxf(m, __shfl_xor(m, 8)); \
            const float inv = 127.0f / m; \
            int q0 = __float2int_rn(ax * inv), q1 = __float2int_rn(ay * inv); \
            int q2 = __float2int_rn(az * inv), q3 = __float2int_rn(aw * inv); \
            if (m == 0.0f) { q0 = q1 = q2 = q3 = 0; } \
            const unsigned pk = (q0 & 0xff) | ((q1 & 0xff) << 8) | \
                                ((q2 & 0xff) << 16) | ((q3 & 0xff) << 24); \
            Y8[(size_t)r * 16 + (c4 >> 2)] = pk; \
            if (c4 == 0) S[r] = m * (1.0f / 127.0f); \
        } }
    STORE(0, acc0) STORE(1, acc1) STORE(2, acc2) STORE(3, acc3)
#undef STORE
}

template<int K, int XBF>
__global__ __launch_bounds__(256) void
k_matmul_b(const void* __restrict__ X, const float* __restrict__ W,
           const float* __restrict__ dis, unsigned* __restrict__ Y8,
           float* __restrict__ S) {
    __shared__ float Wl[K * HH];
    mm_body<K, XBF>(X, W, dis, Y8, S, Wl, blockIdx.x);
}

// fused (R12 exact): blocks [0,MMB) matmul-1; rest place edges
__global__ __launch_bounds__(256) void
k_mm1_place(const float* __restrict__ X, const float* __restrict__ W,
            const float* __restrict__ dis, unsigned* __restrict__ Y8,
            float* __restrict__ S, const int* __restrict__ ei,
            int* __restrict__ cursor, int* __restrict__ srcs) {
    __shared__ float Wl[FF * HH];
    if (blockIdx.x < MMB) {
        mm_body<FF, 0>(X, W, dis, Y8, S, Wl, blockIdx.x);
    } else {
        int e = (blockIdx.x - MMB) * 256 + threadIdx.x;
        if (e < EE) {
            int d = ei[EE + e];
            int p = atomicAdd(&cursor[d], 1);
            srcs[p] = ei[e];
        }
    }
}

// ---------- gather conv: persistent waves; drain-free gather pipeline ----------
// Per node: ONE coalesced index load (srcs[p0+lane]); indices distributed via
// __shfl (lgkmcnt — never drains vmcnt). Batches of 8 rows issue with the
// previous batch still in flight (consume waits vmcnt(4), not 0). Next node's
// row_ptr (scalar/SMEM) + index load issued BEFORE consuming -> per-node RT
// hidden under the consumes. deg>63: rare guarded tail.
template<bool POOL>
__global__ __launch_bounds__(256) void
k_gconv(const int* __restrict__ row_ptr, const int* __restrict__ srcs,
        const float* __restrict__ dis, const unsigned* __restrict__ H8,
        const float* __restrict__ S, const float* __restrict__ b,
        unsigned short* __restrict__ Out, const int* __restrict__ batch,
        float* __restrict__ g) {
    const int lane = threadIdx.x & 63;
    const int li   = lane & 15;       // word index within row
    const int qr   = lane >> 4;       // row slot 0..3 per load
    const float bl = b[lane];

    int node = __builtin_amdgcn_readfirstlane(blockIdx.x * 4 + (threadIdx.x >> 6));
    int p0 = row_ptr[node], p1 = row_ptr[node + 1];
    int idx_l = srcs[p0 + ((lane < p1 - p0) ? lane : 0)];

    while (true) {
        const int deg = p1 - p0;
        const int F   = (deg + 1 < 64) ? deg + 1 : 64;
        int nb = (F + 7) >> 3; if (nb < 2) nb = 2;

        float ac0 = 0.f, ac1 = 0.f, ac2 = 0.f, ac3 = 0.f;
        unsigned uA0, uA1, uB0, uB1;
        float fA0, fA1, fB0, fB1;
        int ia, ib;

#define ISSUE(bi, U0, U1, G0, G1) { \
        const int iA = 8 * (bi) + qr, iB = iA + 4; \
        const int sA = __shfl(idx_l, iA), sB = __shfl(idx_l, iB); \
        const int rA = (iA < deg) ? sA : node; \
        const int rB = (iB < deg) ? sB : node; \
        U0 = H8[(size_t)rA * 16 + li];  G0 = S[rA]; \
        U1 = H8[(size_t)rB * 16 + li];  G1 = S[rB]; }
#define CONS(bi, U0, U1, G0, G1) { \
        const int iA = 8 * (bi) + qr, iB = iA + 4; \
        const float s0 = (iA <= deg) ? G0 : 0.f; \
        const float s1 = (iB <= deg) ? G1 : 0.f; \
        ac0 = fmaf(s0, (float)(signed char)(U0      ), ac0); \
        ac1 = fmaf(s0, (float)(signed char)(U0 >> 8 ), ac1); \
        ac2 = fmaf(s0, (float)(signed char)(U0 >> 16), ac2); \
        ac3 = fmaf(s0, (float)(signed char)(U0 >> 24), ac3); \
        ac0 = fmaf(s1, (float)(signed char)(U1      ), ac0); \
        ac1 = fmaf(s1, (float)(signed char)(U1 >> 8 ), ac1); \
        ac2 = fmaf(s1, (float)(signed char)(U1 >> 16), ac2); \
        ac3 = fmaf(s1, (float)(signed char)(U1 >> 24), ac3); }

        ISSUE(0, uA0, uA1, fA0, fA1) ia = 0;
        ISSUE(1, uB0, uB1, fB0, fB1) ib = 1;
        for (int bi = 2; bi < nb; ++bi) {
            CONS(ia, uA0, uA1, fA0, fA1)
            uA0 = uB0; uA1 = uB1; fA0 = fB0; fA1 = fB1; ia = ib;
            ISSUE(bi, uB0, uB1, fB0, fB1) ib = bi;
        }

        // prefetch next node: scalar row_ptr (lgkmcnt) + index load (stays
        // in flight across the consumes below — newest in vmcnt order).
        const int nnode = node + GCB * 4;
        int np0 = 0, np1 = 0, nidx = 0;
        if (nnode < NN) {
            np0 = row_ptr[nnode]; np1 = row_ptr[nnode + 1];
            nidx = srcs[np0 + ((lane < np1 - np0) ? lane : 0)];
        }

        CONS(ia, uA0, uA1, fA0, fA1)
        CONS(ib, uB0, uB1, fB0, fB1)
#undef ISSUE
#undef CONS
        // rare tail: items 64..deg (self included at i==deg)
        if (deg >= 64) {
            for (int i = 64 + qr; i <= deg; i += 4) {
                const int r = (i < deg) ? srcs[p0 + i] : node;
                const unsigned v = H8[(size_t)r * 16 + li];
                const float s = S[r];
                ac0 = fmaf(s, (float)(signed char)(v      ), ac0);
                ac1 = fmaf(s, (float)(signed char)(v >> 8 ), ac1);
                ac2 = fmaf(s, (float)(signed char)(v >> 16), ac2);
                ac3 = fmaf(s, (float)(signed char)(v >> 24), ac3);
            }
        }

        // reduce across the 4 row slots
        ac0 += __shfl_xor(ac0, 16); ac0 += __shfl_xor(ac0, 32);
        ac1 += __shfl_xor(ac1, 16); ac1 += __shfl_xor(ac1, 32);
        ac2 += __shfl_xor(ac2, 16); ac2 += __shfl_xor(ac2, 32);
        ac3 += __shfl_xor(ac3, 16); ac3 += __shfl_xor(ac3, 32);
        // redistribute so lane holds col = lane (full-wave store)
        const float c0 = __shfl(ac0, lane >> 2);
        const float c1 = __shfl(ac1, lane >> 2);
        const float c2 = __shfl(ac2, lane >> 2);
        const float c3 = __shfl(ac3, lane >> 2);
        const int m = lane & 3;
        const float acc = (m == 0) ? c0 : (m == 1) ? c1 : (m == 2) ? c2 : c3;

        float v = acc * dis[node] + bl;
        v = fmaxf(v, 0.0f);
        if (POOL) {
            unsafeAtomicAdd(&g[(size_t)batch[node] * HH + lane], v);
        } else {
            Out[(size_t)node * HH + lane] = f2bf(v);
        }

        if (nnode >= NN) break;
        node = nnode; p0 = np0; p1 = np1; idx_l = nidx;
    }
}

// ---------- head ----------
__global__ void k_head1(const float* __restrict__ g, const float* __restrict__ W,
                        const float* __restrict__ b, float* __restrict__ g2) {
    const int idx = blockIdx.x * 256 + threadIdx.x;
    const int row = idx >> 6;
    const int col = idx & 63;
    const float* gr = g + (size_t)row * HH;
    float acc = b[col];
#pragma unroll
    for (int k = 0; k < HH; ++k) acc = fmaf(gr[k], W[k * HH + col], acc);
    g2[idx] = acc > 0.0f ? acc : 0.0f;
}

__global__ void k_head2(const float* __restrict__ g2, const float* __restrict__ W,
                        const float* __restrict__ b, float* __restrict__ out) {
    const int r = threadIdx.x;
    if (r >= GG) return;
    const float* gr = g2 + (size_t)r * HH;
    float acc = 0.0f;
#pragma unroll
    for (int k = 0; k < HH; ++k) acc = fmaf(gr[k], W[k], acc);
    out[r] = acc + b[0];
}

extern "C" void kernel_launch(void* const* d_in, const int* in_sizes, int n_in,
                              void* d_out, int out_size, void* d_ws, size_t ws_size,
                              hipStream_t stream) {
    const float* x   = (const float*)d_in[0];
    const int*   ei  = (const int*)d_in[1];
    const int*   bat = (const int*)d_in[2];
    const float* W1  = (const float*)d_in[3];
    const float* b1  = (const float*)d_in[4];
    const float* W2  = (const float*)d_in[5];
    const float* b2  = (const float*)d_in[6];
    const float* Wl1 = (const float*)d_in[7];
    const float* bl1 = (const float*)d_in[8];
    const float* Wl2 = (const float*)d_in[9];
    const float* bl2 = (const float*)d_in[10];
    float* out = (float*)d_out;

    char* w = (char*)d_ws;
    float*    dis     = (float*)(w);                  // 400,128 B
    int*      cnt     = (int*)  (w + 400128);         // 400,128 B
    int*      row_ptr = (int*)  (w + 800256);         // 400,384 B
    int*      cursor  = (int*)  (w + 1200640);        // 400,128 B
    int*      part    = (int*)  (w + 1600768);        // 2,048 B
    int*      srcs    = (int*)  (w + 1602816);        // 4,000,000 B
    float*    S       = (float*)(w + 5602816);        // 400,128 B
    unsigned* H8      = (unsigned*)(w + 6002944);     // 6,400,000 B
    unsigned short* A = (unsigned short*)(w + 12402944); // bf16, 12,800,000 B
    float*    g       = (float*)(w + 25202944);       // pool + head scratch
    float*    g2      = g + GG * HH;

    // ---- CSR build ----
    hipMemsetAsync(cnt, 0, (size_t)NN * sizeof(int), stream);
    k_hist <<<(EE + 255) / 256, 256, 0, stream>>>(ei, cnt);
    k_scan1<<<NB, 256, 0, stream>>>(cnt, part, dis);
    k_scan2<<<1, 512, 0, stream>>>(part);
    k_scan3<<<NB, 256, 0, stream>>>(cnt, part, row_ptr, cursor);

    // ---- conv1 matmul fused with CSR edge placement (R12 structure) ----
    k_mm1_place<<<MMB + (EE + 255) / 256, 256, 0, stream>>>(x, W1, dis, H8, S, ei, cursor, srcs);
    k_gconv<false><<<GCB, 256, 0, stream>>>(row_ptr, srcs, dis, H8, S, b1, A, nullptr, nullptr);

    // ---- conv2 (pool fused) ----
    k_matmul_b<HH, 1><<<MMB, 256, 0, stream>>>(A, W2, dis, H8, S);
    hipMemsetAsync(g, 0, (size_t)GG * HH * sizeof(float), stream);
    k_gconv<true><<<GCB, 256, 0, stream>>>(row_ptr, srcs, dis, H8, S, b2, nullptr, bat, g);

    // ---- head ----
    k_head1<<<(GG * HH) / 256, 256, 0, stream>>>(g, Wl1, bl1, g2);
    k_head2<<<1, 128, 0, stream>>>(g2, Wl2, bl2, out);
}